// Round 3
// baseline (526.857 us; speedup 1.0000x reference)
//
#include <hip/hip_runtime.h>

#define SEQ 2048
#define DM 1024
#define NH 16
#define HD 64
#define BATCH 4
#define M_TOK (BATCH * SEQ)   // 8192

typedef _Float16 f16;
typedef _Float16 f16x8 __attribute__((ext_vector_type(8)));
typedef float f32x4 __attribute__((ext_vector_type(4)));

__device__ __forceinline__ f32x4 mfma16(f16x8 a, f16x8 b, f32x4 c) {
  return __builtin_amdgcn_mfma_f32_16x16x32_f16(a, b, c, 0, 0, 0);
}

__device__ __forceinline__ void gload16(const void* g, void* l) {
  __builtin_amdgcn_global_load_lds((const __attribute__((address_space(1))) void*)g,
                                   (__attribute__((address_space(3))) void*)l, 16, 0, 0);
}

// ---------------- fp32 -> fp16 convert (vectorized) ----------------
__global__ void cvt_f16_kernel(const float* __restrict__ in, f16* __restrict__ out, int n8) {
  int i = blockIdx.x * blockDim.x + threadIdx.x;
  if (i >= n8) return;
  float4 a = ((const float4*)in)[2 * i];
  float4 b = ((const float4*)in)[2 * i + 1];
  f16x8 v;
  v[0] = (f16)a.x; v[1] = (f16)a.y; v[2] = (f16)a.z; v[3] = (f16)a.w;
  v[4] = (f16)b.x; v[5] = (f16)b.y; v[6] = (f16)b.z; v[7] = (f16)b.w;
  *(f16x8*)(out + 8 * i) = v;
}

// ---------------- transpose + convert: W[K][N] f32 -> Wt[N][K] f16 ----------------
__global__ void transpose_cvt_kernel(const float* __restrict__ W, f16* __restrict__ Wt,
                                     int K, int N) {
  __shared__ float t[32][33];
  int tx = threadIdx.x & 31, ty = threadIdx.x >> 5;  // tx 0..31, ty 0..7
  int c0 = blockIdx.x * 32, r0 = blockIdx.y * 32;
#pragma unroll
  for (int i = 0; i < 4; ++i)
    t[ty + 8 * i][tx] = W[(r0 + ty + 8 * i) * N + c0 + tx];
  __syncthreads();
#pragma unroll
  for (int i = 0; i < 4; ++i)
    Wt[(c0 + ty + 8 * i) * K + r0 + tx] = (f16)t[tx][ty + 8 * i];
}

// ---------------- MFMA GEMM: C[M][N] = A[M][K] * Bt[N][K]^T + bias[N] ----------------
// 128x128 tile, BK=64, 4 waves each computing 64x64. XOR-swizzled LDS (128B rows).
template <typename OutT>
__global__ __launch_bounds__(256) void gemm_tn(const f16* __restrict__ A,
                                               const f16* __restrict__ Bt,
                                               const float* __restrict__ bias,
                                               OutT* __restrict__ C, int M, int N, int K) {
  __shared__ f16 Alds[128 * 64];
  __shared__ f16 Blds[128 * 64];
  const int tid = threadIdx.x;
  const int lane = tid & 63, wid = tid >> 6;
  const int l15 = lane & 15, l4 = lane >> 4;
  const int m0 = blockIdx.y * 128, n0 = blockIdx.x * 128;
  const int wr = wid >> 1, wc = wid & 1;

  f32x4 acc[4][4] = {};

  for (int k0 = 0; k0 < K; k0 += 64) {
    __syncthreads();
    // stage A and Bt tiles (16KB each): pre-swizzled global source, linear LDS dest
#pragma unroll
    for (int i = 0; i < 4; ++i) {
      int c = (wid * 4 + i) * 64 + lane;
      int row = c >> 3, cb = (c & 7) << 4;
      int sw = cb ^ ((row & 7) << 4);
      const char* gA = (const char*)(A + ((m0 + row) * K + k0)) + sw;
      gload16(gA, (char*)Alds + ((wid * 4 + i) << 10));
      const char* gB = (const char*)(Bt + ((n0 + row) * K + k0)) + sw;
      gload16(gB, (char*)Blds + ((wid * 4 + i) << 10));
    }
    asm volatile("s_waitcnt vmcnt(0)" ::: "memory");
    __syncthreads();

#pragma unroll
    for (int ks = 0; ks < 2; ++ks) {
      f16x8 af[4], bf[4];
      int cb = ((ks * 4 + l4) << 4);
#pragma unroll
      for (int mi = 0; mi < 4; ++mi) {
        int row = wr * 64 + mi * 16 + l15;
        af[mi] = *(const f16x8*)((const char*)Alds + row * 128 + (cb ^ ((row & 7) << 4)));
      }
#pragma unroll
      for (int ni = 0; ni < 4; ++ni) {
        int row = wc * 64 + ni * 16 + l15;
        bf[ni] = *(const f16x8*)((const char*)Blds + row * 128 + (cb ^ ((row & 7) << 4)));
      }
#pragma unroll
      for (int mi = 0; mi < 4; ++mi)
#pragma unroll
        for (int ni = 0; ni < 4; ++ni)
          acc[mi][ni] = mfma16(af[mi], bf[ni], acc[mi][ni]);
    }
  }

  // epilogue: bias + store. D layout: col = lane&15, row = (lane>>4)*4 + r
#pragma unroll
  for (int ni = 0; ni < 4; ++ni) {
    int col = n0 + wc * 64 + ni * 16 + l15;
    float bv = bias[col];
#pragma unroll
    for (int mi = 0; mi < 4; ++mi)
#pragma unroll
      for (int r = 0; r < 4; ++r) {
        int rowg = m0 + wr * 64 + mi * 16 + l4 * 4 + r;
        C[rowg * N + col] = (OutT)(acc[mi][ni][r] + bv);
      }
  }
}

// ---------------- causal flash attention ----------------
// qkv: [M_TOK][3*DM] f16 ; out: [M_TOK][DM] f16 (layout [b,s,h,d])
// block: 256 threads = 4 waves; 64 q-rows per block (16 per wave); K-tile = 64.
__global__ __launch_bounds__(256) void attn_kernel(const f16* __restrict__ qkv,
                                                   f16* __restrict__ outp) {
  __shared__ f16 Klds[64 * 64];
  __shared__ f16 Vtlds[64 * 64];
  __shared__ f16 Plds[4 * 16 * 64];
  const int tid = threadIdx.x;
  const int lane = tid & 63, wid = tid >> 6;
  const int l15 = lane & 15, l4 = lane >> 4;
  const int bh = blockIdx.x >> 5;
  const int b = bh >> 4, h = bh & 15;
  const int q0 = (blockIdx.x & 31) << 6;

  // Q fragments, held in registers for the whole kernel
  const int qrow = q0 + wid * 16 + l15;
  const f16* qp = qkv + (b * SEQ + qrow) * (3 * DM) + h * HD;
  f16x8 qf0 = *(const f16x8*)(qp + l4 * 8);
  f16x8 qf1 = *(const f16x8*)(qp + 32 + l4 * 8);

  f32x4 o[4] = {};
  float m_run[4], l_run[4];
#pragma unroll
  for (int r = 0; r < 4; ++r) { m_run[r] = -3.0e38f; l_run[r] = 0.f; }

  const int qw_hi = q0 + wid * 16 + 15;
  for (int kt = 0; kt <= q0 + 63; kt += 64) {
    __syncthreads();
    // stage K tile via global_load_lds (pre-swizzled source)
#pragma unroll
    for (int i = 0; i < 2; ++i) {
      int c = (wid * 2 + i) * 64 + lane;
      int row = c >> 3, cb = (c & 7) << 4;
      const char* g = (const char*)(qkv + (b * SEQ + kt + row) * (3 * DM) + DM + h * HD) +
                      (cb ^ ((row & 7) << 4));
      gload16(g, (char*)Klds + ((wid * 2 + i) << 10));
    }
    // stage V transposed (register round-trip, swizzled scalar LDS writes)
#pragma unroll
    for (int i = 0; i < 2; ++i) {
      int c = i * 256 + tid;
      int row = c >> 3, c8 = c & 7;
      f16x8 v = *(const f16x8*)(qkv + (b * SEQ + kt + row) * (3 * DM) + 2 * DM + h * HD + c8 * 8);
#pragma unroll
      for (int e = 0; e < 8; ++e) {
        int dv = c8 * 8 + e;
        *(f16*)((char*)Vtlds + dv * 128 + (((row * 2)) ^ ((dv & 7) << 4))) = v[e];
      }
    }
    asm volatile("s_waitcnt vmcnt(0)" ::: "memory");
    __syncthreads();

    const bool active = (kt <= qw_hi);
    f32x4 p4[4];
    if (active) {
      // scores: S = Q K^T  (16 q-rows x 64 k-cols per wave)
#pragma unroll
      for (int nt = 0; nt < 4; ++nt) {
        f32x4 s = {};
#pragma unroll
        for (int c = 0; c < 2; ++c) {
          int row = nt * 16 + l15;
          int cb = ((c * 4 + l4) << 4);
          f16x8 kf = *(const f16x8*)((const char*)Klds + row * 128 + (cb ^ ((row & 7) << 4)));
          s = mfma16(c == 0 ? qf0 : qf1, kf, s);
        }
#pragma unroll
        for (int r = 0; r < 4; ++r) {
          int q = q0 + wid * 16 + l4 * 4 + r;
          int k = kt + nt * 16 + l15;
          s[r] = (k <= q) ? s[r] * 0.125f : -3.0e38f;
        }
        p4[nt] = s;
      }
      // online softmax: row stats live in the 16 lanes sharing l4
      float mx[4];
#pragma unroll
      for (int r = 0; r < 4; ++r)
        mx[r] = fmaxf(fmaxf(p4[0][r], p4[1][r]), fmaxf(p4[2][r], p4[3][r]));
#pragma unroll
      for (int off = 1; off < 16; off <<= 1)
#pragma unroll
        for (int r = 0; r < 4; ++r)
          mx[r] = fmaxf(mx[r], __shfl_xor(mx[r], off, 64));

      float alpha[4], rs[4];
#pragma unroll
      for (int r = 0; r < 4; ++r) {
        float mn = fmaxf(m_run[r], mx[r]);
        alpha[r] = exp2f((m_run[r] - mn) * 1.44269504f);
        m_run[r] = mn;
        rs[r] = 0.f;
      }
#pragma unroll
      for (int nt = 0; nt < 4; ++nt)
#pragma unroll
        for (int r = 0; r < 4; ++r) {
          float p = exp2f((p4[nt][r] - m_run[r]) * 1.44269504f);
          p4[nt][r] = p;
          rs[r] += p;
        }
#pragma unroll
      for (int off = 1; off < 16; off <<= 1)
#pragma unroll
        for (int r = 0; r < 4; ++r)
          rs[r] += __shfl_xor(rs[r], off, 64);
#pragma unroll
      for (int r = 0; r < 4; ++r)
        l_run[r] = l_run[r] * alpha[r] + rs[r];
#pragma unroll
      for (int t = 0; t < 4; ++t)
#pragma unroll
        for (int r = 0; r < 4; ++r)
          o[t][r] = o[t][r] * alpha[r];
      // write P tile to per-wave LDS (swizzled), as fp16
#pragma unroll
      for (int nt = 0; nt < 4; ++nt)
#pragma unroll
        for (int r = 0; r < 4; ++r) {
          int row = l4 * 4 + r;
          int cb = (nt * 16 + l15) * 2;
          *(f16*)((char*)Plds + (wid << 11) + row * 128 + (cb ^ ((row & 7) << 4))) =
              (f16)p4[nt][r];
        }
    }
    __syncthreads();  // P visibility within wave (uniform barrier across all waves)
    if (active) {
      // O += P V : A-frag = P rows (l&15), B-frag = Vt rows (dv)
#pragma unroll
      for (int c = 0; c < 2; ++c) {
        int cb = ((c * 4 + l4) << 4);
        int prow = l15;
        f16x8 pf = *(const f16x8*)((const char*)Plds + (wid << 11) + prow * 128 +
                                   (cb ^ ((prow & 7) << 4)));
#pragma unroll
        for (int t = 0; t < 4; ++t) {
          int row = t * 16 + l15;
          f16x8 vf = *(const f16x8*)((const char*)Vtlds + row * 128 + (cb ^ ((row & 7) << 4)));
          o[t] = mfma16(pf, vf, o[t]);
        }
      }
    }
  }

  // epilogue: normalize and store [b, q, h, dv]
#pragma unroll
  for (int t = 0; t < 4; ++t)
#pragma unroll
    for (int r = 0; r < 4; ++r) {
      int q = q0 + wid * 16 + l4 * 4 + r;
      int dv = t * 16 + l15;
      outp[(b * SEQ + q) * DM + h * HD + dv] = (f16)(o[t][r] / l_run[r]);
    }
}

// ---------------- launch ----------------
extern "C" void kernel_launch(void* const* d_in, const int* in_sizes, int n_in,
                              void* d_out, int out_size, void* d_ws, size_t ws_size,
                              hipStream_t stream) {
  const float* x = (const float*)d_in[0];
  const float* Wqkv = (const float*)d_in[1];
  const float* bqkv = (const float*)d_in[2];
  const float* Wout = (const float*)d_in[3];
  const float* bout = (const float*)d_in[4];
  float* out = (float*)d_out;

  char* ws = (char*)d_ws;
  f16* xh = (f16*)(ws);                              // 8192*1024*2   = 16.78 MB
  f16* qkvh = (f16*)(ws + 16777216);                 // 8192*3072*2   = 50.33 MB
  f16* wqkvT = (f16*)(ws + 16777216 + 50331648);     // 3072*1024*2   =  6.29 MB
  f16* woutT = (f16*)(ws + 16777216 + 50331648 + 6291456);  // 1024*1024*2 = 2.10 MB
  f16* attno = xh;  // reuse x_h region (dead after GEMM1)

  // 1. convert x to f16
  cvt_f16_kernel<<<(M_TOK * DM / 8 + 255) / 256, 256, 0, stream>>>(x, xh, M_TOK * DM / 8);
  // 2. transpose+convert weights: W[K][N] -> Wt[N][K]
  transpose_cvt_kernel<<<dim3(3 * DM / 32, DM / 32), 256, 0, stream>>>(Wqkv, wqkvT, DM, 3 * DM);
  transpose_cvt_kernel<<<dim3(DM / 32, DM / 32), 256, 0, stream>>>(Wout, woutT, DM, DM);
  // 3. QKV projection: qkv = xh @ Wqkv + bqkv   [8192, 3072] f16
  gemm_tn<f16><<<dim3(3 * DM / 128, M_TOK / 128), 256, 0, stream>>>(xh, wqkvT, bqkv, qkvh,
                                                                    M_TOK, 3 * DM, DM);
  // 4. causal attention
  attn_kernel<<<BATCH * NH * (SEQ / 64), 256, 0, stream>>>(qkvh, attno);
  // 5. output projection: out = attno @ Wout + bout  [8192, 1024] f32
  gemm_tn<float><<<dim3(DM / 128, M_TOK / 128), 256, 0, stream>>>(attno, woutT, bout, out,
                                                                  M_TOK, DM, DM);
}

// Round 5
// 369.683 us; speedup vs baseline: 1.4252x; 1.4252x over previous
//
#include <hip/hip_runtime.h>

#define SEQ 2048
#define DM 1024
#define NH 16
#define HD 64
#define BATCH 4
#define M_TOK (BATCH * SEQ)   // 8192

typedef _Float16 f16;
typedef _Float16 f16x8 __attribute__((ext_vector_type(8)));
typedef float f32x4 __attribute__((ext_vector_type(4)));

__device__ __forceinline__ f32x4 mfma16(f16x8 a, f16x8 b, f32x4 c) {
  return __builtin_amdgcn_mfma_f32_16x16x32_f16(a, b, c, 0, 0, 0);
}

__device__ __forceinline__ void gload16(const void* g, void* l) {
  __builtin_amdgcn_global_load_lds((const __attribute__((address_space(1))) void*)g,
                                   (__attribute__((address_space(3))) void*)l, 16, 0, 0);
}

// ---------------- fp32 -> fp16 convert (vectorized) ----------------
__global__ void cvt_f16_kernel(const float* __restrict__ in, f16* __restrict__ out, int n8) {
  int i = blockIdx.x * blockDim.x + threadIdx.x;
  if (i >= n8) return;
  float4 a = ((const float4*)in)[2 * i];
  float4 b = ((const float4*)in)[2 * i + 1];
  f16x8 v;
  v[0] = (f16)a.x; v[1] = (f16)a.y; v[2] = (f16)a.z; v[3] = (f16)a.w;
  v[4] = (f16)b.x; v[5] = (f16)b.y; v[6] = (f16)b.z; v[7] = (f16)b.w;
  *(f16x8*)(out + 8 * i) = v;
}

// ---------------- transpose + convert: W[K][N] f32 -> Wt[N][K] f16 ----------------
__global__ void transpose_cvt_kernel(const float* __restrict__ W, f16* __restrict__ Wt,
                                     int K, int N) {
  __shared__ float t[32][33];
  int tx = threadIdx.x & 31, ty = threadIdx.x >> 5;
  int c0 = blockIdx.x * 32, r0 = blockIdx.y * 32;
#pragma unroll
  for (int i = 0; i < 4; ++i)
    t[ty + 8 * i][tx] = W[(r0 + ty + 8 * i) * N + c0 + tx];
  __syncthreads();
#pragma unroll
  for (int i = 0; i < 4; ++i)
    Wt[(c0 + ty + 8 * i) * K + r0 + tx] = (f16)t[tx][ty + 8 * i];
}

// ---------------- MFMA GEMM: C[M][N] = A[M][K] * Bt[N][K]^T + bias[N] ----------------
// 128x128 tile, BK=64, 4 waves each computing 64x64. XOR-swizzled LDS (128B rows).
// SPLIT_V: columns >= 2048 (the V third of QKV) are written transposed into Vt[b*1024+hdv][s].
template <typename OutT, bool SPLIT_V>
__global__ __launch_bounds__(256) void gemm_tn(const f16* __restrict__ A,
                                               const f16* __restrict__ Bt,
                                               const float* __restrict__ bias,
                                               OutT* __restrict__ C, f16* __restrict__ Vt,
                                               int M, int N, int K, int ldc) {
  __shared__ f16 Alds[128 * 64];
  __shared__ f16 Blds[128 * 64];
  const int tid = threadIdx.x;
  const int lane = tid & 63, wid = tid >> 6;
  const int l15 = lane & 15, l4 = lane >> 4;
  const int m0 = blockIdx.y * 128, n0 = blockIdx.x * 128;
  const int wr = wid >> 1, wc = wid & 1;

  f32x4 acc[4][4] = {};

  for (int k0 = 0; k0 < K; k0 += 64) {
    __syncthreads();
#pragma unroll
    for (int i = 0; i < 4; ++i) {
      int c = (wid * 4 + i) * 64 + lane;
      int row = c >> 3, cb = (c & 7) << 4;
      int sw = cb ^ ((row & 7) << 4);
      const char* gA = (const char*)(A + ((size_t)(m0 + row) * K + k0)) + sw;
      gload16(gA, (char*)Alds + ((wid * 4 + i) << 10));
      const char* gB = (const char*)(Bt + ((size_t)(n0 + row) * K + k0)) + sw;
      gload16(gB, (char*)Blds + ((wid * 4 + i) << 10));
    }
    asm volatile("s_waitcnt vmcnt(0)" ::: "memory");
    __syncthreads();

#pragma unroll
    for (int ks = 0; ks < 2; ++ks) {
      f16x8 af[4], bf[4];
      int cb = ((ks * 4 + l4) << 4);
#pragma unroll
      for (int mi = 0; mi < 4; ++mi) {
        int row = wr * 64 + mi * 16 + l15;
        af[mi] = *(const f16x8*)((const char*)Alds + row * 128 + (cb ^ ((row & 7) << 4)));
      }
#pragma unroll
      for (int ni = 0; ni < 4; ++ni) {
        int row = wc * 64 + ni * 16 + l15;
        bf[ni] = *(const f16x8*)((const char*)Blds + row * 128 + (cb ^ ((row & 7) << 4)));
      }
#pragma unroll
      for (int mi = 0; mi < 4; ++mi)
#pragma unroll
        for (int ni = 0; ni < 4; ++ni)
          acc[mi][ni] = mfma16(af[mi], bf[ni], acc[mi][ni]);
    }
  }

  // epilogue: bias + store. D layout: col = lane&15, row = (lane>>4)*4 + r
#pragma unroll
  for (int ni = 0; ni < 4; ++ni) {
    int col = n0 + wc * 64 + ni * 16 + l15;
    float bv = bias[col];
#pragma unroll
    for (int mi = 0; mi < 4; ++mi)
#pragma unroll
      for (int r = 0; r < 4; ++r) {
        int rowg = m0 + wr * 64 + mi * 16 + l4 * 4 + r;
        float val = acc[mi][ni][r] + bv;
        if (SPLIT_V && col >= 2 * DM) {
          // V column: write transposed [b*1024 + h*64+dv][s]
          int hdv = col - 2 * DM;
          int b = rowg >> 11, s = rowg & (SEQ - 1);
          Vt[(size_t)(b * 1024 + hdv) * SEQ + s] = (f16)val;
        } else {
          C[(size_t)rowg * ldc + col] = (OutT)val;
        }
      }
  }
}

// ---------------- causal flash attention ----------------
// qkh: [M_TOK][2048] f16 (Q cols 0..1023, K cols 1024..2047, per-head 64)
// vtg: [B*NH*64][SEQ] f16 (V transposed: row = b*1024 + h*64 + dv, col = s)
// out: [M_TOK][DM] f16 ([b,s,h,d])
// 256 thr = 4 waves; 64 q-rows/block; KV tile 64; 2-phase double-buffered staging.
__global__ __launch_bounds__(256) void attn_kernel(const f16* __restrict__ qkh,
                                                   const f16* __restrict__ vtg,
                                                   f16* __restrict__ outp) {
  __shared__ f16 Klds[2][64 * 64];
  __shared__ f16 Vlds[2][64 * 64];
  __shared__ f16 Plds[4][16 * 64];
  const int tid = threadIdx.x;
  const int lane = tid & 63, wid = tid >> 6;
  const int l15 = lane & 15, l4 = lane >> 4;
  // XCD-chunked swizzle (2048 blocks, 8 XCDs -> 256-block chunks = 8 bh groups/XCD)
  const int blk = blockIdx.x;
  const int swz = (blk & 7) * 256 + (blk >> 3);
  const int bh = swz >> 5;
  const int b = bh >> 4, h = bh & 15;
  const int q0 = (31 - (swz & 31)) << 6;  // heavy blocks first within each chunk

  // Q fragments in registers for the whole kernel
  const int qrow = q0 + wid * 16 + l15;
  const f16* qp = qkh + (size_t)(b * SEQ + qrow) * 2048 + h * HD;
  const f16x8 qf0 = *(const f16x8*)(qp + l4 * 8);
  const f16x8 qf1 = *(const f16x8*)(qp + 32 + l4 * 8);

  // staging source bases (byte addresses)
  const char* kbase = (const char*)qkh + ((size_t)(b * SEQ) * 2048 + 1024 + h * HD) * 2;
  const char* vbase = (const char*)vtg + ((size_t)(bh * 64) * SEQ) * 2;
  // per-lane staging geometry (2 chunks per wave per tensor)
  int srow[2], ssw[2], schunk[2];
#pragma unroll
  for (int i = 0; i < 2; ++i) {
    int c = (wid * 2 + i) * 64 + lane;
    srow[i] = c >> 3;
    int cb = (c & 7) << 4;
    ssw[i] = cb ^ ((srow[i] & 7) << 4);
    schunk[i] = (wid * 2 + i) << 10;
  }

  f32x4 o[4] = {};
  float m_run[4], l_run[4];
#pragma unroll
  for (int r = 0; r < 4; ++r) { m_run[r] = -3.0e38f; l_run[r] = 0.f; }

  f16x8 onef;
#pragma unroll
  for (int e = 0; e < 8; ++e) onef[e] = (f16)1.0f;

  const int ntile = (q0 >> 6) + 1;

  // prologue: stage tile 0 into buffer 0
#pragma unroll
  for (int i = 0; i < 2; ++i) {
    gload16(kbase + (size_t)srow[i] * 4096 + ssw[i], (char*)Klds[0] + schunk[i]);
    gload16(vbase + (size_t)srow[i] * 4096 + ssw[i], (char*)Vlds[0] + schunk[i]);
  }
  __syncthreads();

  for (int t = 0; t < ntile; ++t) {
    const int cur = t & 1;
    const int kt = t << 6;
    // issue next-tile staging (overlaps with compute; drained by end-of-iter barrier)
    if (t + 1 < ntile) {
      const int kn = kt + 64;
#pragma unroll
      for (int i = 0; i < 2; ++i) {
        gload16(kbase + (size_t)(kn + srow[i]) * 4096 + ssw[i], (char*)Klds[cur ^ 1] + schunk[i]);
        gload16(vbase + (size_t)srow[i] * 4096 + kn * 2 + ssw[i], (char*)Vlds[cur ^ 1] + schunk[i]);
      }
    }

    // ---- QK^T ----
    f32x4 p4[4];
#pragma unroll
    for (int nt = 0; nt < 4; ++nt) {
      f32x4 s = {};
#pragma unroll
      for (int c = 0; c < 2; ++c) {
        int row = nt * 16 + l15;
        int cb = ((c * 4 + l4) << 4);
        f16x8 kf = *(const f16x8*)((const char*)Klds[cur] + row * 128 + (cb ^ ((row & 7) << 4)));
        s = mfma16(c == 0 ? qf0 : qf1, kf, s);
      }
#pragma unroll
      for (int r = 0; r < 4; ++r) {
        int q = q0 + wid * 16 + l4 * 4 + r;
        int k = kt + nt * 16 + l15;
        s[r] = (k <= q) ? s[r] * 0.125f : -3.0e38f;
      }
      p4[nt] = s;
    }

    // ---- online softmax: max over 16 lanes (l15 group) ----
    float mx[4];
#pragma unroll
    for (int r = 0; r < 4; ++r)
      mx[r] = fmaxf(fmaxf(p4[0][r], p4[1][r]), fmaxf(p4[2][r], p4[3][r]));
#pragma unroll
    for (int off = 1; off < 16; off <<= 1)
#pragma unroll
      for (int r = 0; r < 4; ++r)
        mx[r] = fmaxf(mx[r], __shfl_xor(mx[r], off, 64));

    float alpha[4];
#pragma unroll
    for (int r = 0; r < 4; ++r) {
      float mn = fmaxf(m_run[r], mx[r]);
      alpha[r] = exp2f((m_run[r] - mn) * 1.44269504f);
      m_run[r] = mn;
    }
    // P = exp(S - m), write to per-wave LDS (swizzled f16); row-sum comes from ones-MFMA
#pragma unroll
    for (int nt = 0; nt < 4; ++nt)
#pragma unroll
      for (int r = 0; r < 4; ++r) {
        float p = exp2f((p4[nt][r] - m_run[r]) * 1.44269504f);
        int row = l4 * 4 + r;
        int cb = (nt * 16 + l15) * 2;
        *(f16*)((char*)Plds[wid] + row * 128 + (cb ^ ((row & 7) << 4))) = (f16)p;
      }
#pragma unroll
    for (int tt = 0; tt < 4; ++tt)
#pragma unroll
      for (int r = 0; r < 4; ++r)
        o[tt][r] *= alpha[r];

    // ---- O += P V ; l-rowsum via ones-MFMA (lands in accumulator row layout) ----
    f32x4 accl = {};
#pragma unroll
    for (int c = 0; c < 2; ++c) {
      int cb = ((c * 4 + l4) << 4);
      int prow = l15;
      f16x8 pf = *(const f16x8*)((const char*)Plds[wid] + prow * 128 + (cb ^ ((prow & 7) << 4)));
#pragma unroll
      for (int tt = 0; tt < 4; ++tt) {
        int row = tt * 16 + l15;
        f16x8 vf = *(const f16x8*)((const char*)Vlds[cur] + row * 128 + (cb ^ ((row & 7) << 4)));
        o[tt] = mfma16(pf, vf, o[tt]);
      }
      accl = mfma16(pf, onef, accl);
    }
#pragma unroll
    for (int r = 0; r < 4; ++r)
      l_run[r] = l_run[r] * alpha[r] + accl[r];

    __syncthreads();  // drains next-tile staging (vmcnt0) + cross-wave LDS coherence
  }

  // epilogue: normalize and store [b, q, h, dv]
#pragma unroll
  for (int tt = 0; tt < 4; ++tt)
#pragma unroll
    for (int r = 0; r < 4; ++r) {
      int q = q0 + wid * 16 + l4 * 4 + r;
      int dv = tt * 16 + l15;
      outp[(size_t)(b * SEQ + q) * DM + h * HD + dv] = (f16)(o[tt][r] / l_run[r]);
    }
}

// ---------------- launch ----------------
extern "C" void kernel_launch(void* const* d_in, const int* in_sizes, int n_in,
                              void* d_out, int out_size, void* d_ws, size_t ws_size,
                              hipStream_t stream) {
  const float* x = (const float*)d_in[0];
  const float* Wqkv = (const float*)d_in[1];
  const float* bqkv = (const float*)d_in[2];
  const float* Wout = (const float*)d_in[3];
  const float* bout = (const float*)d_in[4];
  float* out = (float*)d_out;

  char* ws = (char*)d_ws;
  f16* xh = (f16*)(ws);                               // 16.78 MB  [8192][1024]
  f16* qkh = (f16*)(ws + 16777216);                   // 33.55 MB  [8192][2048] (Q|K)
  f16* vt = (f16*)(ws + 16777216 + 33554432);         // 16.78 MB  [4096][2048] (V^T)
  f16* wqkvT = (f16*)(ws + 16777216 + 33554432 + 16777216);            // 6.29 MB
  f16* woutT = (f16*)(ws + 16777216 + 33554432 + 16777216 + 6291456);  // 2.10 MB
  f16* attno = xh;  // reuse x_h region (dead after GEMM1)

  // 1. convert x to f16
  cvt_f16_kernel<<<(M_TOK * DM / 8 + 255) / 256, 256, 0, stream>>>(x, xh, M_TOK * DM / 8);
  // 2. transpose+convert weights
  transpose_cvt_kernel<<<dim3(3 * DM / 32, DM / 32), 256, 0, stream>>>(Wqkv, wqkvT, DM, 3 * DM);
  transpose_cvt_kernel<<<dim3(DM / 32, DM / 32), 256, 0, stream>>>(Wout, woutT, DM, DM);
  // 3. QKV projection: Q,K -> qkh (stride 2048); V -> vt (transposed)
  gemm_tn<f16, true><<<dim3(3 * DM / 128, M_TOK / 128), 256, 0, stream>>>(
      xh, wqkvT, bqkv, qkh, vt, M_TOK, 3 * DM, DM, 2048);
  // 4. causal attention
  attn_kernel<<<BATCH * NH * (SEQ / 64), 256, 0, stream>>>(qkh, vt, attno);
  // 5. output projection
  gemm_tn<float, false><<<dim3(DM / 128, M_TOK / 128), 256, 0, stream>>>(
      attno, woutT, bout, out, nullptr, M_TOK, DM, DM, DM);
}

// Round 7
// 342.304 us; speedup vs baseline: 1.5391x; 1.0800x over previous
//
#include <hip/hip_runtime.h>

#define SEQ 2048
#define DM 1024
#define NH 16
#define HD 64
#define BATCH 4
#define M_TOK (BATCH * SEQ)   // 8192

typedef _Float16 f16;
typedef _Float16 f16x8 __attribute__((ext_vector_type(8)));
typedef _Float16 f16x4 __attribute__((ext_vector_type(4)));
typedef float f32x4 __attribute__((ext_vector_type(4)));
typedef float f32x16 __attribute__((ext_vector_type(16)));

__device__ __forceinline__ f32x4 mfma16(f16x8 a, f16x8 b, f32x4 c) {
  return __builtin_amdgcn_mfma_f32_16x16x32_f16(a, b, c, 0, 0, 0);
}
__device__ __forceinline__ f32x16 mfma32(f16x8 a, f16x8 b, f32x16 c) {
  return __builtin_amdgcn_mfma_f32_32x32x16_f16(a, b, c, 0, 0, 0);
}

__device__ __forceinline__ void gload16(const void* g, void* l) {
  __builtin_amdgcn_global_load_lds((const __attribute__((address_space(1))) void*)g,
                                   (__attribute__((address_space(3))) void*)l, 16, 0, 0);
}

// ---------------- fp32 -> fp16 convert (vectorized) ----------------
__global__ void cvt_f16_kernel(const float* __restrict__ in, f16* __restrict__ out, int n8) {
  int i = blockIdx.x * blockDim.x + threadIdx.x;
  if (i >= n8) return;
  float4 a = ((const float4*)in)[2 * i];
  float4 b = ((const float4*)in)[2 * i + 1];
  f16x8 v;
  v[0] = (f16)a.x; v[1] = (f16)a.y; v[2] = (f16)a.z; v[3] = (f16)a.w;
  v[4] = (f16)b.x; v[5] = (f16)b.y; v[6] = (f16)b.z; v[7] = (f16)b.w;
  *(f16x8*)(out + 8 * i) = v;
}

// ---------------- transpose + convert: W[K][N] f32 -> Wt[N][K] f16 ----------------
__global__ void transpose_cvt_kernel(const float* __restrict__ W, f16* __restrict__ Wt,
                                     int K, int N) {
  __shared__ float t[32][33];
  int tx = threadIdx.x & 31, ty = threadIdx.x >> 5;
  int c0 = blockIdx.x * 32, r0 = blockIdx.y * 32;
#pragma unroll
  for (int i = 0; i < 4; ++i)
    t[ty + 8 * i][tx] = W[(r0 + ty + 8 * i) * N + c0 + tx];
  __syncthreads();
#pragma unroll
  for (int i = 0; i < 4; ++i)
    Wt[(c0 + ty + 8 * i) * K + r0 + tx] = (f16)t[tx][ty + 8 * i];
}

// ---------------- MFMA GEMM: C[M][N] = A[M][K] * Bt[N][K]^T + bias[N] ----------------
// 128x128 tile, BK=64, 4 waves each computing 64x64. XOR-swizzled LDS (128B rows).
// SPLIT_V: columns >= 2048 (the V third of QKV) are written transposed into Vt[b*1024+hdv][s].
template <typename OutT, bool SPLIT_V>
__global__ __launch_bounds__(256) void gemm_tn(const f16* __restrict__ A,
                                               const f16* __restrict__ Bt,
                                               const float* __restrict__ bias,
                                               OutT* __restrict__ C, f16* __restrict__ Vt,
                                               int M, int N, int K, int ldc) {
  __shared__ f16 Alds[128 * 64];
  __shared__ f16 Blds[128 * 64];
  const int tid = threadIdx.x;
  const int lane = tid & 63, wid = tid >> 6;
  const int l15 = lane & 15, l4 = lane >> 4;
  const int m0 = blockIdx.y * 128, n0 = blockIdx.x * 128;
  const int wr = wid >> 1, wc = wid & 1;

  f32x4 acc[4][4] = {};

  for (int k0 = 0; k0 < K; k0 += 64) {
    __syncthreads();
#pragma unroll
    for (int i = 0; i < 4; ++i) {
      int c = (wid * 4 + i) * 64 + lane;
      int row = c >> 3, cb = (c & 7) << 4;
      int sw = cb ^ ((row & 7) << 4);
      const char* gA = (const char*)(A + ((size_t)(m0 + row) * K + k0)) + sw;
      gload16(gA, (char*)Alds + ((wid * 4 + i) << 10));
      const char* gB = (const char*)(Bt + ((size_t)(n0 + row) * K + k0)) + sw;
      gload16(gB, (char*)Blds + ((wid * 4 + i) << 10));
    }
    asm volatile("s_waitcnt vmcnt(0)" ::: "memory");
    __syncthreads();

#pragma unroll
    for (int ks = 0; ks < 2; ++ks) {
      f16x8 af[4], bf[4];
      int cb = ((ks * 4 + l4) << 4);
#pragma unroll
      for (int mi = 0; mi < 4; ++mi) {
        int row = wr * 64 + mi * 16 + l15;
        af[mi] = *(const f16x8*)((const char*)Alds + row * 128 + (cb ^ ((row & 7) << 4)));
      }
#pragma unroll
      for (int ni = 0; ni < 4; ++ni) {
        int row = wc * 64 + ni * 16 + l15;
        bf[ni] = *(const f16x8*)((const char*)Blds + row * 128 + (cb ^ ((row & 7) << 4)));
      }
#pragma unroll
      for (int mi = 0; mi < 4; ++mi)
#pragma unroll
        for (int ni = 0; ni < 4; ++ni)
          acc[mi][ni] = mfma16(af[mi], bf[ni], acc[mi][ni]);
    }
  }

  // epilogue: bias + store. D layout: col = lane&15, row = (lane>>4)*4 + r
#pragma unroll
  for (int ni = 0; ni < 4; ++ni) {
    int col = n0 + wc * 64 + ni * 16 + l15;
    float bv = bias[col];
#pragma unroll
    for (int mi = 0; mi < 4; ++mi)
#pragma unroll
      for (int r = 0; r < 4; ++r) {
        int rowg = m0 + wr * 64 + mi * 16 + l4 * 4 + r;
        float val = acc[mi][ni][r] + bv;
        if (SPLIT_V && col >= 2 * DM) {
          int hdv = col - 2 * DM;
          int b = rowg >> 11, s = rowg & (SEQ - 1);
          Vt[(size_t)(b * 1024 + hdv) * SEQ + s] = (f16)val;
        } else {
          C[(size_t)rowg * ldc + col] = (OutT)val;
        }
      }
  }
}

// ---------------- causal flash attention: swapped-QK^T, in-register softmax ----------
// qkh: [M_TOK][2048] f16 (Q cols 0..1023, K cols 1024..2047)
// vtg: [B*NH*64][SEQ] f16 (V transposed)
// out: [M_TOK][DM] f16 ([b,s,h,d])
// 256 thr = 4 waves; QBLK=128 (32 q/wave via 32x32 MFMA); KV tile 64; double-buffered.
// S^T = mfma32(K, Q): lane owns q = lane&31; k rows split across lane / lane+32.
union H2u { struct { f16 lo, hi; } s; unsigned u; };
union F8u { f16x8 v; unsigned u[4]; };

__global__ __launch_bounds__(256) void attn_kernel(const f16* __restrict__ qkh,
                                                   const f16* __restrict__ vtg,
                                                   f16* __restrict__ outp) {
  __shared__ f16 Klds[2][64 * 64];
  __shared__ f16 Vlds[2][64 * 64];
  const int tid = threadIdx.x;
  const int lane = tid & 63, wid = tid >> 6;
  const int lq = lane & 31, hi = lane >> 5;
  // bijective XCD swizzle: 1024 blocks = 8 XCDs x 128
  const int blk = blockIdx.x;
  const int swz = (blk & 7) * 128 + (blk >> 3);
  const int bh = swz >> 4;
  const int b = bh >> 4, h = bh & 15;
  const int q0 = (15 - (swz & 15)) << 7;  // heavy q-blocks first
  const int q0w = q0 + wid * 32;
  const int q_g = q0w + lq;

  // Q fragment (B-operand): col=q=lane&31, k(d) = s*16 + hi*8 + j. Pre-scale by 0.125 (exact).
  const f16* qp = qkh + (size_t)(b * SEQ + q_g) * 2048 + h * HD;
  f16x8 qf[4];
#pragma unroll
  for (int s = 0; s < 4; ++s) {
    qf[s] = *(const f16x8*)(qp + s * 16 + hi * 8);
    qf[s] = qf[s] * (f16)0.125f;
  }

  const char* kbase = (const char*)qkh + ((size_t)(b * SEQ) * 2048 + 1024 + h * HD) * 2;
  const char* vbase = (const char*)vtg + ((size_t)(bh * 64) * SEQ) * 2;
  int srow[2], ssw[2], schunk[2];
#pragma unroll
  for (int i = 0; i < 2; ++i) {
    int c = (wid * 2 + i) * 64 + lane;
    srow[i] = c >> 3;
    ssw[i] = ((c & 7) << 4) ^ ((srow[i] & 7) << 4);
    schunk[i] = (wid * 2 + i) << 10;
  }

  f32x16 o0 = {}, o1 = {};
  float m_run = -3.0e38f, l_run = 0.f;
  const int ntile = (q0 >> 6) + 2;          // block-level tiles
  const int ntw = (q0w >> 6) + 1;           // this wave's tiles
  const float L2E = 1.44269504f;

  // prologue: stage tile 0 into buffer 0
#pragma unroll
  for (int i = 0; i < 2; ++i) {
    gload16(kbase + (size_t)srow[i] * 4096 + ssw[i], (char*)Klds[0] + schunk[i]);
    gload16(vbase + (size_t)srow[i] * 4096 + ssw[i], (char*)Vlds[0] + schunk[i]);
  }
  __syncthreads();

  for (int t = 0; t < ntile; ++t) {
    const int cur = t & 1;
    const int kt = t << 6;
    if (t + 1 < ntile) {
      const int kn = kt + 64;
#pragma unroll
      for (int i = 0; i < 2; ++i) {
        gload16(kbase + (size_t)(kn + srow[i]) * 4096 + ssw[i], (char*)Klds[cur ^ 1] + schunk[i]);
        gload16(vbase + (size_t)srow[i] * 4096 + kn * 2 + ssw[i], (char*)Vlds[cur ^ 1] + schunk[i]);
      }
    }

    if (t < ntw) {
      // ---- S^T = K * Q : st0 = k rows 0..31, st1 = k rows 32..63 (of this tile) ----
      f32x16 st0 = {}, st1 = {};
#pragma unroll
      for (int s = 0; s < 4; ++s) {
        int cb = ((2 * s + hi) << 4);
        f16x8 kf0 = *(const f16x8*)((const char*)Klds[cur] + lq * 128 + (cb ^ ((lq & 7) << 4)));
        f16x8 kf1 =
            *(const f16x8*)((const char*)Klds[cur] + (32 + lq) * 128 + (cb ^ ((lq & 7) << 4)));
        st0 = mfma32(kf0, qf[s], st0);
        st1 = mfma32(kf1, qf[s], st1);
      }
      // ---- causal mask: only the wave's diagonal tile needs it ----
      if (t == ntw - 1) {
#pragma unroll
        for (int r = 0; r < 16; ++r) {
          int kl = (r & 3) + 8 * (r >> 2) + 4 * hi;
          if (kt + kl > q_g) st0[r] = -3.0e38f;
          if (kt + 32 + kl > q_g) st1[r] = -3.0e38f;
        }
      }
      // ---- in-register row max (31 in-lane + 1 cross-half) ----
      float mx = st0[0];
#pragma unroll
      for (int r = 1; r < 16; ++r) mx = fmaxf(mx, st0[r]);
#pragma unroll
      for (int r = 0; r < 16; ++r) mx = fmaxf(mx, st1[r]);
      mx = fmaxf(mx, __shfl_xor(mx, 32));
      // ---- rescale only when max grows ----
      if (__any(mx > m_run)) {
        float mn = fmaxf(m_run, mx);
        float al = exp2f((m_run - mn) * L2E);
        m_run = mn;
        l_run *= al;
        o0 = o0 * al;
        o1 = o1 * al;
      }
      // ---- p = exp(s - m) in-register ----
      const float negmL = -m_run * L2E;
#pragma unroll
      for (int r = 0; r < 16; ++r) st0[r] = exp2f(fmaf(st0[r], L2E, negmL));
#pragma unroll
      for (int r = 0; r < 16; ++r) st1[r] = exp2f(fmaf(st1[r], L2E, negmL));
      // ---- row sum ----
      float sm = st0[0];
#pragma unroll
      for (int r = 1; r < 16; ++r) sm += st0[r];
#pragma unroll
      for (int r = 0; r < 16; ++r) sm += st1[r];
      sm += __shfl_xor(sm, 32);
      l_run += sm;

      // ---- O^T += V^T * P^T : build B-frag (P^T) per 16-k step via pack + half-swap ----
#pragma unroll
      for (int s = 0; s < 4; ++s) {
        const f32x16& ps = (s < 2) ? st0 : st1;
        const int r0 = 8 * (s & 1);
        H2u a0, a1, a2, a3;
        a0.s.lo = (f16)ps[r0 + 0]; a0.s.hi = (f16)ps[r0 + 1];
        a1.s.lo = (f16)ps[r0 + 2]; a1.s.hi = (f16)ps[r0 + 3];
        a2.s.lo = (f16)ps[r0 + 4]; a2.s.hi = (f16)ps[r0 + 5];
        a3.s.lo = (f16)ps[r0 + 6]; a3.s.hi = (f16)ps[r0 + 7];
        unsigned ux = __shfl_xor(a0.u, 32), vx = __shfl_xor(a1.u, 32);
        unsigned wx = __shfl_xor(a2.u, 32), zx = __shfl_xor(a3.u, 32);
        F8u pb;
        pb.u[0] = hi ? wx : a0.u;   // k = 8*hi + {0,1}
        pb.u[1] = hi ? zx : a1.u;   // k = 8*hi + {2,3}
        pb.u[2] = hi ? a2.u : ux;   // k = 8*hi + {4,5}
        pb.u[3] = hi ? a3.u : vx;   // k = 8*hi + {6,7}
        int vb = ((2 * s + hi) << 4);
        f16x8 vf0 = *(const f16x8*)((const char*)Vlds[cur] + lq * 128 + (vb ^ ((lq & 7) << 4)));
        f16x8 vf1 =
            *(const f16x8*)((const char*)Vlds[cur] + (32 + lq) * 128 + (vb ^ ((lq & 7) << 4)));
        o0 = mfma32(vf0, pb.v, o0);
        o1 = mfma32(vf1, pb.v, o1);
      }
    }
    __syncthreads();  // drains next-tile staging; uniform across waves
  }

  // ---- epilogue: normalize, store [b, q, h, dv] (runs of 4 contiguous dv) ----
  float rl = 1.0f / l_run;
  f16* outb = outp + (size_t)(b * SEQ + q_g) * DM + h * HD;
#pragma unroll
  for (int dvt = 0; dvt < 2; ++dvt) {
    const f32x16& ov = dvt ? o1 : o0;
#pragma unroll
    for (int rg = 0; rg < 4; ++rg) {
      f16x4 w4;
#pragma unroll
      for (int j = 0; j < 4; ++j) w4[j] = (f16)(ov[rg * 4 + j] * rl);
      *(f16x4*)(outb + dvt * 32 + 8 * rg + 4 * hi) = w4;
    }
  }
}

// ---------------- launch ----------------
extern "C" void kernel_launch(void* const* d_in, const int* in_sizes, int n_in,
                              void* d_out, int out_size, void* d_ws, size_t ws_size,
                              hipStream_t stream) {
  const float* x = (const float*)d_in[0];
  const float* Wqkv = (const float*)d_in[1];
  const float* bqkv = (const float*)d_in[2];
  const float* Wout = (const float*)d_in[3];
  const float* bout = (const float*)d_in[4];
  float* out = (float*)d_out;

  char* ws = (char*)d_ws;
  f16* xh = (f16*)(ws);                               // 16.78 MB  [8192][1024]
  f16* qkh = (f16*)(ws + 16777216);                   // 33.55 MB  [8192][2048] (Q|K)
  f16* vt = (f16*)(ws + 16777216 + 33554432);         // 16.78 MB  [4096][2048] (V^T)
  f16* wqkvT = (f16*)(ws + 16777216 + 33554432 + 16777216);            // 6.29 MB
  f16* woutT = (f16*)(ws + 16777216 + 33554432 + 16777216 + 6291456);  // 2.10 MB
  f16* attno = xh;  // reuse x_h region (dead after GEMM1)

  cvt_f16_kernel<<<(M_TOK * DM / 8 + 255) / 256, 256, 0, stream>>>(x, xh, M_TOK * DM / 8);
  transpose_cvt_kernel<<<dim3(3 * DM / 32, DM / 32), 256, 0, stream>>>(Wqkv, wqkvT, DM, 3 * DM);
  transpose_cvt_kernel<<<dim3(DM / 32, DM / 32), 256, 0, stream>>>(Wout, woutT, DM, DM);
  gemm_tn<f16, true><<<dim3(3 * DM / 128, M_TOK / 128), 256, 0, stream>>>(
      xh, wqkvT, bqkv, qkh, vt, M_TOK, 3 * DM, DM, 2048);
  attn_kernel<<<BATCH * NH * (SEQ / 128), 256, 0, stream>>>(qkh, vt, attno);
  gemm_tn<float, false><<<dim3(DM / 128, M_TOK / 128), 256, 0, stream>>>(
      attno, woutT, bout, out, nullptr, M_TOK, DM, DM, DM);
}

// Round 8
// 321.593 us; speedup vs baseline: 1.6383x; 1.0644x over previous
//
#include <hip/hip_runtime.h>

#define SEQ 2048
#define DM 1024
#define NH 16
#define HD 64
#define BATCH 4
#define M_TOK (BATCH * SEQ)   // 8192

typedef _Float16 f16;
typedef _Float16 f16x8 __attribute__((ext_vector_type(8)));
typedef _Float16 f16x4 __attribute__((ext_vector_type(4)));
typedef float f32x4 __attribute__((ext_vector_type(4)));
typedef float f32x16 __attribute__((ext_vector_type(16)));

__device__ __forceinline__ f32x4 mfma16(f16x8 a, f16x8 b, f32x4 c) {
  return __builtin_amdgcn_mfma_f32_16x16x32_f16(a, b, c, 0, 0, 0);
}
__device__ __forceinline__ f32x16 mfma32(f16x8 a, f16x8 b, f32x16 c) {
  return __builtin_amdgcn_mfma_f32_32x32x16_f16(a, b, c, 0, 0, 0);
}

__device__ __forceinline__ void gload16(const void* g, void* l) {
  __builtin_amdgcn_global_load_lds((const __attribute__((address_space(1))) void*)g,
                                   (__attribute__((address_space(3))) void*)l, 16, 0, 0);
}

// ---------------- fp32 -> fp16 convert (vectorized) ----------------
__global__ void cvt_f16_kernel(const float* __restrict__ in, f16* __restrict__ out, int n8) {
  int i = blockIdx.x * blockDim.x + threadIdx.x;
  if (i >= n8) return;
  float4 a = ((const float4*)in)[2 * i];
  float4 b = ((const float4*)in)[2 * i + 1];
  f16x8 v;
  v[0] = (f16)a.x; v[1] = (f16)a.y; v[2] = (f16)a.z; v[3] = (f16)a.w;
  v[4] = (f16)b.x; v[5] = (f16)b.y; v[6] = (f16)b.z; v[7] = (f16)b.w;
  *(f16x8*)(out + 8 * i) = v;
}

// ---------------- transpose + convert: W[K][N] f32 -> Wt[N][K] f16 ----------------
__global__ void transpose_cvt_kernel(const float* __restrict__ W, f16* __restrict__ Wt,
                                     int K, int N) {
  __shared__ float t[32][33];
  int tx = threadIdx.x & 31, ty = threadIdx.x >> 5;
  int c0 = blockIdx.x * 32, r0 = blockIdx.y * 32;
#pragma unroll
  for (int i = 0; i < 4; ++i)
    t[ty + 8 * i][tx] = W[(r0 + ty + 8 * i) * N + c0 + tx];
  __syncthreads();
#pragma unroll
  for (int i = 0; i < 4; ++i)
    Wt[(c0 + ty + 8 * i) * K + r0 + tx] = (f16)t[tx][ty + 8 * i];
}

// ---------------- MFMA GEMM: C[M][N] = A[M][K] * Bt[N][K]^T + bias[N] ----------------
// 128x128 tile, BK=64, 4 waves each computing 64x64. XOR-swizzled LDS (128B rows).
// SPLIT_V: columns >= 2048 (the V third of QKV) are written transposed into Vt[b*1024+hdv][s].
template <typename OutT, bool SPLIT_V>
__global__ __launch_bounds__(256) void gemm_tn(const f16* __restrict__ A,
                                               const f16* __restrict__ Bt,
                                               const float* __restrict__ bias,
                                               OutT* __restrict__ C, f16* __restrict__ Vt,
                                               int M, int N, int K, int ldc) {
  __shared__ f16 Alds[128 * 64];
  __shared__ f16 Blds[128 * 64];
  const int tid = threadIdx.x;
  const int lane = tid & 63, wid = tid >> 6;
  const int l15 = lane & 15, l4 = lane >> 4;
  const int m0 = blockIdx.y * 128, n0 = blockIdx.x * 128;
  const int wr = wid >> 1, wc = wid & 1;

  f32x4 acc[4][4] = {};

  for (int k0 = 0; k0 < K; k0 += 64) {
    __syncthreads();
#pragma unroll
    for (int i = 0; i < 4; ++i) {
      int c = (wid * 4 + i) * 64 + lane;
      int row = c >> 3, cb = (c & 7) << 4;
      int sw = cb ^ ((row & 7) << 4);
      const char* gA = (const char*)(A + ((size_t)(m0 + row) * K + k0)) + sw;
      gload16(gA, (char*)Alds + ((wid * 4 + i) << 10));
      const char* gB = (const char*)(Bt + ((size_t)(n0 + row) * K + k0)) + sw;
      gload16(gB, (char*)Blds + ((wid * 4 + i) << 10));
    }
    asm volatile("s_waitcnt vmcnt(0)" ::: "memory");
    __syncthreads();

#pragma unroll
    for (int ks = 0; ks < 2; ++ks) {
      f16x8 af[4], bf[4];
      int cb = ((ks * 4 + l4) << 4);
#pragma unroll
      for (int mi = 0; mi < 4; ++mi) {
        int row = wr * 64 + mi * 16 + l15;
        af[mi] = *(const f16x8*)((const char*)Alds + row * 128 + (cb ^ ((row & 7) << 4)));
      }
#pragma unroll
      for (int ni = 0; ni < 4; ++ni) {
        int row = wc * 64 + ni * 16 + l15;
        bf[ni] = *(const f16x8*)((const char*)Blds + row * 128 + (cb ^ ((row & 7) << 4)));
      }
#pragma unroll
      for (int mi = 0; mi < 4; ++mi)
#pragma unroll
        for (int ni = 0; ni < 4; ++ni)
          acc[mi][ni] = mfma16(af[mi], bf[ni], acc[mi][ni]);
    }
  }

  // epilogue: bias + store. D layout: col = lane&15, row = (lane>>4)*4 + r
#pragma unroll
  for (int ni = 0; ni < 4; ++ni) {
    int col = n0 + wc * 64 + ni * 16 + l15;
    float bv = bias[col];
#pragma unroll
    for (int mi = 0; mi < 4; ++mi)
#pragma unroll
      for (int r = 0; r < 4; ++r) {
        int rowg = m0 + wr * 64 + mi * 16 + l4 * 4 + r;
        float val = acc[mi][ni][r] + bv;
        if (SPLIT_V && col >= 2 * DM) {
          int hdv = col - 2 * DM;
          int b = rowg >> 11, s = rowg & (SEQ - 1);
          Vt[(size_t)(b * 1024 + hdv) * SEQ + s] = (f16)val;
        } else {
          C[(size_t)rowg * ldc + col] = (OutT)val;
        }
      }
  }
}

// ---------------- causal flash attention: swapped-QK^T, in-register softmax ----------
// qkh: [M_TOK][2048] f16 (Q cols 0..1023, K cols 1024..2047)
// vtg: [B*NH*64][SEQ] f16 (V transposed)
// out: [M_TOK][DM] f16 ([b,s,h,d])
// 256 thr = 4 waves; QBLK=128 (32 q/wave via 32x32 MFMA); KV tile 64; double-buffered.
// S^T = mfma32(K, Q): lane owns q = lane&31; k rows split across lane / lane+32.
union H2u { struct { f16 lo, hi; } s; unsigned u; };
union F8u { f16x8 v; unsigned u[4]; };

__global__ __launch_bounds__(256) void attn_kernel(const f16* __restrict__ qkh,
                                                   const f16* __restrict__ vtg,
                                                   f16* __restrict__ outp) {
  __shared__ f16 Klds[2][64 * 64];
  __shared__ f16 Vlds[2][64 * 64];
  const int tid = threadIdx.x;
  const int lane = tid & 63, wid = tid >> 6;
  const int lq = lane & 31, hi = lane >> 5;
  // XCD-aware mapping + CU-level causal-depth balancing.
  // blk%8 = XCD; within an XCD, sequential CU fill gives CU c local slots
  // {c, c+32, c+64, c+96} -> (qp fixed, bq in an even-or-odd 4-set). XOR-ing
  // q-index with h(bq), where each 4-set of h splits into complement pairs
  // {h, 15-h}, makes every CU's 4 blocks sum to 30 q-index units (68 KV tiles)
  // while staying bijective per bh.
  const int blk = blockIdx.x;
  const int xcd = blk & 7, sl = blk >> 3;
  const int bq = sl >> 4, qp = sl & 15;
  const int bh = xcd * 8 + bq;
  const int b = bh >> 4, h = bh & 15;
  const int hb = ((bq & 2) ? 15 : 0) ^ ((bq & 1) ? 3 : 0) ^ ((bq & 4) ? 5 : 0);
  const int q0 = (qp ^ hb) << 7;
  const int q0w = q0 + wid * 32;
  const int q_g = q0w + lq;

  // Q fragment (B-operand): col=q=lane&31, k(d) = s*16 + hi*8 + j. Pre-scale by 0.125 (exact).
  const f16* qp_ptr = qkh + (size_t)(b * SEQ + q_g) * 2048 + h * HD;
  f16x8 qf[4];
#pragma unroll
  for (int s = 0; s < 4; ++s) {
    qf[s] = *(const f16x8*)(qp_ptr + s * 16 + hi * 8);
    qf[s] = qf[s] * (f16)0.125f;
  }

  const char* kbase = (const char*)qkh + ((size_t)(b * SEQ) * 2048 + 1024 + h * HD) * 2;
  const char* vbase = (const char*)vtg + ((size_t)(bh * 64) * SEQ) * 2;
  int srow[2], ssw[2], schunk[2];
#pragma unroll
  for (int i = 0; i < 2; ++i) {
    int c = (wid * 2 + i) * 64 + lane;
    srow[i] = c >> 3;
    ssw[i] = ((c & 7) << 4) ^ ((srow[i] & 7) << 4);
    schunk[i] = (wid * 2 + i) << 10;
  }

  f32x16 o0 = {}, o1 = {};
  float m_run = -3.0e38f, l_run = 0.f;
  const int ntile = (q0 >> 6) + 2;          // block-level tiles
  const int ntw = (q0w >> 6) + 1;           // this wave's tiles
  const float L2E = 1.44269504f;

  // prologue: stage tile 0 into buffer 0
#pragma unroll
  for (int i = 0; i < 2; ++i) {
    gload16(kbase + (size_t)srow[i] * 4096 + ssw[i], (char*)Klds[0] + schunk[i]);
    gload16(vbase + (size_t)srow[i] * 4096 + ssw[i], (char*)Vlds[0] + schunk[i]);
  }
  __syncthreads();

  for (int t = 0; t < ntile; ++t) {
    const int cur = t & 1;
    const int kt = t << 6;
    if (t + 1 < ntile) {
      const int kn = kt + 64;
#pragma unroll
      for (int i = 0; i < 2; ++i) {
        gload16(kbase + (size_t)(kn + srow[i]) * 4096 + ssw[i], (char*)Klds[cur ^ 1] + schunk[i]);
        gload16(vbase + (size_t)srow[i] * 4096 + kn * 2 + ssw[i], (char*)Vlds[cur ^ 1] + schunk[i]);
      }
    }

    if (t < ntw) {
      // ---- S^T = K * Q : st0 = k rows 0..31, st1 = k rows 32..63 (of this tile) ----
      f32x16 st0 = {}, st1 = {};
#pragma unroll
      for (int s = 0; s < 4; ++s) {
        int cb = ((2 * s + hi) << 4);
        f16x8 kf0 = *(const f16x8*)((const char*)Klds[cur] + lq * 128 + (cb ^ ((lq & 7) << 4)));
        f16x8 kf1 =
            *(const f16x8*)((const char*)Klds[cur] + (32 + lq) * 128 + (cb ^ ((lq & 7) << 4)));
        st0 = mfma32(kf0, qf[s], st0);
        st1 = mfma32(kf1, qf[s], st1);
      }
      // ---- causal mask: only the wave's diagonal tile needs it ----
      if (t == ntw - 1) {
#pragma unroll
        for (int r = 0; r < 16; ++r) {
          int kl = (r & 3) + 8 * (r >> 2) + 4 * hi;
          if (kt + kl > q_g) st0[r] = -3.0e38f;
          if (kt + 32 + kl > q_g) st1[r] = -3.0e38f;
        }
      }
      // ---- in-register row max (31 in-lane + 1 cross-half) ----
      float mx = st0[0];
#pragma unroll
      for (int r = 1; r < 16; ++r) mx = fmaxf(mx, st0[r]);
#pragma unroll
      for (int r = 0; r < 16; ++r) mx = fmaxf(mx, st1[r]);
      mx = fmaxf(mx, __shfl_xor(mx, 32));
      // ---- rescale only when max grows ----
      if (__any(mx > m_run)) {
        float mn = fmaxf(m_run, mx);
        float al = exp2f((m_run - mn) * L2E);
        m_run = mn;
        l_run *= al;
        o0 = o0 * al;
        o1 = o1 * al;
      }
      // ---- p = exp(s - m) in-register ----
      const float negmL = -m_run * L2E;
#pragma unroll
      for (int r = 0; r < 16; ++r) st0[r] = exp2f(fmaf(st0[r], L2E, negmL));
#pragma unroll
      for (int r = 0; r < 16; ++r) st1[r] = exp2f(fmaf(st1[r], L2E, negmL));
      // ---- row sum ----
      float sm = st0[0];
#pragma unroll
      for (int r = 1; r < 16; ++r) sm += st0[r];
#pragma unroll
      for (int r = 0; r < 16; ++r) sm += st1[r];
      sm += __shfl_xor(sm, 32);
      l_run += sm;

      // ---- O^T += V^T * P^T : build B-frag (P^T) per 16-k step via pack + half-swap ----
#pragma unroll
      for (int s = 0; s < 4; ++s) {
        const f32x16& ps = (s < 2) ? st0 : st1;
        const int r0 = 8 * (s & 1);
        H2u a0, a1, a2, a3;
        a0.s.lo = (f16)ps[r0 + 0]; a0.s.hi = (f16)ps[r0 + 1];
        a1.s.lo = (f16)ps[r0 + 2]; a1.s.hi = (f16)ps[r0 + 3];
        a2.s.lo = (f16)ps[r0 + 4]; a2.s.hi = (f16)ps[r0 + 5];
        a3.s.lo = (f16)ps[r0 + 6]; a3.s.hi = (f16)ps[r0 + 7];
        unsigned ux = __shfl_xor(a0.u, 32), vx = __shfl_xor(a1.u, 32);
        unsigned wx = __shfl_xor(a2.u, 32), zx = __shfl_xor(a3.u, 32);
        F8u pb;
        pb.u[0] = hi ? wx : a0.u;   // k = 8*hi + {0,1}
        pb.u[1] = hi ? zx : a1.u;   // k = 8*hi + {2,3}
        pb.u[2] = hi ? a2.u : ux;   // k = 8*hi + {4,5}
        pb.u[3] = hi ? a3.u : vx;   // k = 8*hi + {6,7}
        int vb = ((2 * s + hi) << 4);
        f16x8 vf0 = *(const f16x8*)((const char*)Vlds[cur] + lq * 128 + (vb ^ ((lq & 7) << 4)));
        f16x8 vf1 =
            *(const f16x8*)((const char*)Vlds[cur] + (32 + lq) * 128 + (vb ^ ((lq & 7) << 4)));
        o0 = mfma32(vf0, pb.v, o0);
        o1 = mfma32(vf1, pb.v, o1);
      }
    }
    __syncthreads();  // drains next-tile staging; uniform across waves
  }

  // ---- epilogue: normalize, store [b, q, h, dv] (runs of 4 contiguous dv) ----
  float rl = 1.0f / l_run;
  f16* outb = outp + (size_t)(b * SEQ + q_g) * DM + h * HD;
#pragma unroll
  for (int dvt = 0; dvt < 2; ++dvt) {
    const f32x16& ov = dvt ? o1 : o0;
#pragma unroll
    for (int rg = 0; rg < 4; ++rg) {
      f16x4 w4;
#pragma unroll
      for (int j = 0; j < 4; ++j) w4[j] = (f16)(ov[rg * 4 + j] * rl);
      *(f16x4*)(outb + dvt * 32 + 8 * rg + 4 * hi) = w4;
    }
  }
}

// ---------------- launch ----------------
extern "C" void kernel_launch(void* const* d_in, const int* in_sizes, int n_in,
                              void* d_out, int out_size, void* d_ws, size_t ws_size,
                              hipStream_t stream) {
  const float* x = (const float*)d_in[0];
  const float* Wqkv = (const float*)d_in[1];
  const float* bqkv = (const float*)d_in[2];
  const float* Wout = (const float*)d_in[3];
  const float* bout = (const float*)d_in[4];
  float* out = (float*)d_out;

  char* ws = (char*)d_ws;
  f16* xh = (f16*)(ws);                               // 16.78 MB  [8192][1024]
  f16* qkh = (f16*)(ws + 16777216);                   // 33.55 MB  [8192][2048] (Q|K)
  f16* vt = (f16*)(ws + 16777216 + 33554432);         // 16.78 MB  [4096][2048] (V^T)
  f16* wqkvT = (f16*)(ws + 16777216 + 33554432 + 16777216);            // 6.29 MB
  f16* woutT = (f16*)(ws + 16777216 + 33554432 + 16777216 + 6291456);  // 2.10 MB
  f16* attno = xh;  // reuse x_h region (dead after GEMM1)

  cvt_f16_kernel<<<(M_TOK * DM / 8 + 255) / 256, 256, 0, stream>>>(x, xh, M_TOK * DM / 8);
  transpose_cvt_kernel<<<dim3(3 * DM / 32, DM / 32), 256, 0, stream>>>(Wqkv, wqkvT, DM, 3 * DM);
  transpose_cvt_kernel<<<dim3(DM / 32, DM / 32), 256, 0, stream>>>(Wout, woutT, DM, DM);
  gemm_tn<f16, true><<<dim3(3 * DM / 128, M_TOK / 128), 256, 0, stream>>>(
      xh, wqkvT, bqkv, qkh, vt, M_TOK, 3 * DM, DM, 2048);
  attn_kernel<<<BATCH * NH * (SEQ / 128), 256, 0, stream>>>(qkh, vt, attno);
  gemm_tn<float, false><<<dim3(DM / 128, M_TOK / 128), 256, 0, stream>>>(
      attno, woutT, bout, out, nullptr, M_TOK, DM, DM, DM);
}

// Round 9
// 300.652 us; speedup vs baseline: 1.7524x; 1.0697x over previous
//
#include <hip/hip_runtime.h>

#define SEQ 2048
#define DM 1024
#define NH 16
#define HD 64
#define BATCH 4
#define M_TOK (BATCH * SEQ)   // 8192

typedef _Float16 f16;
typedef _Float16 f16x8 __attribute__((ext_vector_type(8)));
typedef _Float16 f16x4 __attribute__((ext_vector_type(4)));
typedef float f32x4 __attribute__((ext_vector_type(4)));
typedef float f32x16 __attribute__((ext_vector_type(16)));

__device__ __forceinline__ f32x4 mfma16(f16x8 a, f16x8 b, f32x4 c) {
  return __builtin_amdgcn_mfma_f32_16x16x32_f16(a, b, c, 0, 0, 0);
}
__device__ __forceinline__ f32x16 mfma32(f16x8 a, f16x8 b, f32x16 c) {
  return __builtin_amdgcn_mfma_f32_32x32x16_f16(a, b, c, 0, 0, 0);
}

__device__ __forceinline__ void gload16(const void* g, void* l) {
  __builtin_amdgcn_global_load_lds((const __attribute__((address_space(1))) void*)g,
                                   (__attribute__((address_space(3))) void*)l, 16, 0, 0);
}

// ---------------- fp32 -> fp16 convert (vectorized) ----------------
__global__ void cvt_f16_kernel(const float* __restrict__ in, f16* __restrict__ out, int n8) {
  int i = blockIdx.x * blockDim.x + threadIdx.x;
  if (i >= n8) return;
  float4 a = ((const float4*)in)[2 * i];
  float4 b = ((const float4*)in)[2 * i + 1];
  f16x8 v;
  v[0] = (f16)a.x; v[1] = (f16)a.y; v[2] = (f16)a.z; v[3] = (f16)a.w;
  v[4] = (f16)b.x; v[5] = (f16)b.y; v[6] = (f16)b.z; v[7] = (f16)b.w;
  *(f16x8*)(out + 8 * i) = v;
}

// ---------------- transpose + convert: W[K][N] f32 -> Wt[N][K] f16 ----------------
__global__ void transpose_cvt_kernel(const float* __restrict__ W, f16* __restrict__ Wt,
                                     int K, int N) {
  __shared__ float t[32][33];
  int tx = threadIdx.x & 31, ty = threadIdx.x >> 5;
  int c0 = blockIdx.x * 32, r0 = blockIdx.y * 32;
#pragma unroll
  for (int i = 0; i < 4; ++i)
    t[ty + 8 * i][tx] = W[(r0 + ty + 8 * i) * N + c0 + tx];
  __syncthreads();
#pragma unroll
  for (int i = 0; i < 4; ++i)
    Wt[(c0 + ty + 8 * i) * K + r0 + tx] = (f16)t[tx][ty + 8 * i];
}

// ---------------- MFMA GEMM: C[M][N] = A[M][K] * Bt[N][K]^T + bias[N] ----------------
// 128x128 tile, BK=64, 4 waves each computing 64x64. XOR-swizzled LDS (128B rows).
// SPLIT_V: columns >= 2048 (the V third of QKV) are written transposed into Vt[b*1024+hdv][s].
template <typename OutT, bool SPLIT_V>
__global__ __launch_bounds__(256) void gemm_tn(const f16* __restrict__ A,
                                               const f16* __restrict__ Bt,
                                               const float* __restrict__ bias,
                                               OutT* __restrict__ C, f16* __restrict__ Vt,
                                               int M, int N, int K, int ldc) {
  __shared__ f16 Alds[128 * 64];
  __shared__ f16 Blds[128 * 64];
  const int tid = threadIdx.x;
  const int lane = tid & 63, wid = tid >> 6;
  const int l15 = lane & 15, l4 = lane >> 4;
  const int m0 = blockIdx.y * 128, n0 = blockIdx.x * 128;
  const int wr = wid >> 1, wc = wid & 1;

  f32x4 acc[4][4] = {};

  for (int k0 = 0; k0 < K; k0 += 64) {
    __syncthreads();
#pragma unroll
    for (int i = 0; i < 4; ++i) {
      int c = (wid * 4 + i) * 64 + lane;
      int row = c >> 3, cb = (c & 7) << 4;
      int sw = cb ^ ((row & 7) << 4);
      const char* gA = (const char*)(A + ((size_t)(m0 + row) * K + k0)) + sw;
      gload16(gA, (char*)Alds + ((wid * 4 + i) << 10));
      const char* gB = (const char*)(Bt + ((size_t)(n0 + row) * K + k0)) + sw;
      gload16(gB, (char*)Blds + ((wid * 4 + i) << 10));
    }
    asm volatile("s_waitcnt vmcnt(0)" ::: "memory");
    __syncthreads();

#pragma unroll
    for (int ks = 0; ks < 2; ++ks) {
      f16x8 af[4], bf[4];
      int cb = ((ks * 4 + l4) << 4);
#pragma unroll
      for (int mi = 0; mi < 4; ++mi) {
        int row = wr * 64 + mi * 16 + l15;
        af[mi] = *(const f16x8*)((const char*)Alds + row * 128 + (cb ^ ((row & 7) << 4)));
      }
#pragma unroll
      for (int ni = 0; ni < 4; ++ni) {
        int row = wc * 64 + ni * 16 + l15;
        bf[ni] = *(const f16x8*)((const char*)Blds + row * 128 + (cb ^ ((row & 7) << 4)));
      }
#pragma unroll
      for (int mi = 0; mi < 4; ++mi)
#pragma unroll
        for (int ni = 0; ni < 4; ++ni)
          acc[mi][ni] = mfma16(af[mi], bf[ni], acc[mi][ni]);
    }
  }

  // epilogue: bias + store. D layout: col = lane&15, row = (lane>>4)*4 + r
#pragma unroll
  for (int ni = 0; ni < 4; ++ni) {
    int col = n0 + wc * 64 + ni * 16 + l15;
    float bv = bias[col];
#pragma unroll
    for (int mi = 0; mi < 4; ++mi)
#pragma unroll
      for (int r = 0; r < 4; ++r) {
        int rowg = m0 + wr * 64 + mi * 16 + l4 * 4 + r;
        float val = acc[mi][ni][r] + bv;
        if (SPLIT_V && col >= 2 * DM) {
          int hdv = col - 2 * DM;
          int b = rowg >> 11, s = rowg & (SEQ - 1);
          Vt[(size_t)(b * 1024 + hdv) * SEQ + s] = (f16)val;
        } else {
          C[(size_t)rowg * ldc + col] = (OutT)val;
        }
      }
  }
}

// ---------------- causal flash attention: swapped-QK^T, paired q-tiles ----------
// qkh: [M_TOK][2048] f16 (Q cols 0..1023, K cols 1024..2047)
// vtg: [B*NH*64][SEQ] f16 (V transposed)
// out: [M_TOK][DM] f16 ([b,s,h,d])
// 256 thr = 4 waves; each block processes q-tile pair (15-p, p) SEQUENTIALLY:
// total KV iterations = (2(15-p)+2) + (2p+2) = 34 for EVERY block -> uniform work,
// no causal tail. Grid 512 = 2 blocks/CU, all resident. Phase-2 KV tiles are a
// subset of phase-1's (qS < qD) -> L2-hot re-reads.
// S^T = mfma32(K, Q): lane owns q = lane&31; k rows split across lane / lane+32.
union H2u { struct { f16 lo, hi; } s; unsigned u; };
union F8u { f16x8 v; unsigned u[4]; };

__global__ __launch_bounds__(256) void attn_kernel(const f16* __restrict__ qkh,
                                                   const f16* __restrict__ vtg,
                                                   f16* __restrict__ outp) {
  __shared__ f16 Klds[2][64 * 64];
  __shared__ f16 Vlds[2][64 * 64];
  const int tid = threadIdx.x;
  const int lane = tid & 63, wid = tid >> 6;
  const int lq = lane & 31, hi = lane >> 5;
  // 512 blocks: xcd = blk&7; within XCD, 8 bh x 8 pairs (same-bh blocks share L2 K/V)
  const int blk = blockIdx.x;
  const int xcd = blk & 7, rr = blk >> 3;
  const int bh = xcd * 8 + (rr & 7);
  const int p = rr >> 3;                 // pair index 0..7
  const int b = bh >> 4, h = bh & 15;
  const int qD = 15 - p, qS = p;         // deep first, then shallow

  const char* kbase = (const char*)qkh + ((size_t)(b * SEQ) * 2048 + 1024 + h * HD) * 2;
  const char* vbase = (const char*)vtg + ((size_t)(bh * 64) * SEQ) * 2;
  int srow[2], ssw[2], schunk[2];
#pragma unroll
  for (int i = 0; i < 2; ++i) {
    int c = (wid * 2 + i) * 64 + lane;
    srow[i] = c >> 3;
    ssw[i] = ((c & 7) << 4) ^ ((srow[i] & 7) << 4);
    schunk[i] = (wid * 2 + i) << 10;
  }

  // phase state
  int q0 = qD << 7;
  int q_g = q0 + wid * 32 + lq;
  int ntw = ((q0 + wid * 32) >> 6) + 1;
  f16x8 qf[4];
  f32x16 o0 = {}, o1 = {};
  float m_run = -3.0e38f, l_run = 0.f;
  const float L2E = 1.44269504f;

  auto load_q = [&]() {
    const f16* qp_ptr = qkh + (size_t)(b * SEQ + q_g) * 2048 + h * HD;
#pragma unroll
    for (int s = 0; s < 4; ++s) {
      qf[s] = *(const f16x8*)(qp_ptr + s * 16 + hi * 8);
      qf[s] = qf[s] * (f16)0.125f;  // exact pre-scale
    }
  };
  auto store_out = [&]() {
    float rl = 1.0f / l_run;
    f16* outb = outp + (size_t)(b * SEQ + q_g) * DM + h * HD;
#pragma unroll
    for (int dvt = 0; dvt < 2; ++dvt) {
      const f32x16& ov = dvt ? o1 : o0;
#pragma unroll
      for (int rg = 0; rg < 4; ++rg) {
        f16x4 w4;
#pragma unroll
        for (int j = 0; j < 4; ++j) w4[j] = (f16)(ov[rg * 4 + j] * rl);
        *(f16x4*)(outb + dvt * 32 + 8 * rg + 4 * hi) = w4;
      }
    }
  };

  load_q();
  const int ntD = 2 * qD + 2;
  const int ntT = ntD + 2 * qS + 2;      // == 34 for every block

  // prologue: stage KV tile 0 into buffer 0
#pragma unroll
  for (int i = 0; i < 2; ++i) {
    gload16(kbase + (size_t)srow[i] * 4096 + ssw[i], (char*)Klds[0] + schunk[i]);
    gload16(vbase + (size_t)srow[i] * 4096 + ssw[i], (char*)Vlds[0] + schunk[i]);
  }
  __syncthreads();

  for (int t = 0; t < ntT; ++t) {
    const int cur = t & 1;
    // prefetch next iteration's KV tile (phase-2 wraps to tile 0 seamlessly)
    if (t + 1 < ntT) {
      const int kn = (t + 1 < ntD) ? (t + 1) : (t + 1 - ntD);
#pragma unroll
      for (int i = 0; i < 2; ++i) {
        gload16(kbase + (size_t)(kn * 64 + srow[i]) * 4096 + ssw[i],
                (char*)Klds[cur ^ 1] + schunk[i]);
        gload16(vbase + (size_t)srow[i] * 4096 + (size_t)kn * 128 + ssw[i],
                (char*)Vlds[cur ^ 1] + schunk[i]);
      }
    }
    // phase switch (block-uniform): store deep output, reset, load shallow Q
    if (t == ntD) {
      store_out();
#pragma unroll
      for (int r2 = 0; r2 < 16; ++r2) { o0[r2] = 0.f; o1[r2] = 0.f; }
      m_run = -3.0e38f;
      l_run = 0.f;
      q0 = qS << 7;
      q_g = q0 + wid * 32 + lq;
      ntw = ((q0 + wid * 32) >> 6) + 1;
      load_q();
    }
    const int tt = (t >= ntD) ? (t - ntD) : t;

    if (tt < ntw) {
      const int kt = tt << 6;
      // ---- S^T = K * Q ----
      f32x16 st0 = {}, st1 = {};
#pragma unroll
      for (int s = 0; s < 4; ++s) {
        int cb = ((2 * s + hi) << 4);
        f16x8 kf0 = *(const f16x8*)((const char*)Klds[cur] + lq * 128 + (cb ^ ((lq & 7) << 4)));
        f16x8 kf1 =
            *(const f16x8*)((const char*)Klds[cur] + (32 + lq) * 128 + (cb ^ ((lq & 7) << 4)));
        st0 = mfma32(kf0, qf[s], st0);
        st1 = mfma32(kf1, qf[s], st1);
      }
      // ---- causal mask on the wave's diagonal tile ----
      if (tt == ntw - 1) {
#pragma unroll
        for (int r = 0; r < 16; ++r) {
          int kl = (r & 3) + 8 * (r >> 2) + 4 * hi;
          if (kt + kl > q_g) st0[r] = -3.0e38f;
          if (kt + 32 + kl > q_g) st1[r] = -3.0e38f;
        }
      }
      // ---- row max (31 in-lane + 1 cross-half) ----
      float mx = st0[0];
#pragma unroll
      for (int r = 1; r < 16; ++r) mx = fmaxf(mx, st0[r]);
#pragma unroll
      for (int r = 0; r < 16; ++r) mx = fmaxf(mx, st1[r]);
      mx = fmaxf(mx, __shfl_xor(mx, 32));
      // ---- defer-max (T13, THR=8): rescale only when max grows materially ----
      if (__any(mx - m_run > 8.0f)) {
        float mn = fmaxf(m_run, mx);
        float al = exp2f((m_run - mn) * L2E);
        m_run = mn;
        l_run *= al;
        o0 = o0 * al;
        o1 = o1 * al;
      }
      // ---- p = exp(s - m) in-register ----
      const float negmL = -m_run * L2E;
#pragma unroll
      for (int r = 0; r < 16; ++r) st0[r] = exp2f(fmaf(st0[r], L2E, negmL));
#pragma unroll
      for (int r = 0; r < 16; ++r) st1[r] = exp2f(fmaf(st1[r], L2E, negmL));
      // ---- row sum ----
      float sm = st0[0];
#pragma unroll
      for (int r = 1; r < 16; ++r) sm += st0[r];
#pragma unroll
      for (int r = 0; r < 16; ++r) sm += st1[r];
      sm += __shfl_xor(sm, 32);
      l_run += sm;

      // ---- O^T += V^T * P^T : pack + half-swap per 16-k step ----
#pragma unroll
      for (int s = 0; s < 4; ++s) {
        const f32x16& ps = (s < 2) ? st0 : st1;
        const int r0 = 8 * (s & 1);
        H2u a0, a1, a2, a3;
        a0.s.lo = (f16)ps[r0 + 0]; a0.s.hi = (f16)ps[r0 + 1];
        a1.s.lo = (f16)ps[r0 + 2]; a1.s.hi = (f16)ps[r0 + 3];
        a2.s.lo = (f16)ps[r0 + 4]; a2.s.hi = (f16)ps[r0 + 5];
        a3.s.lo = (f16)ps[r0 + 6]; a3.s.hi = (f16)ps[r0 + 7];
        unsigned ux = __shfl_xor(a0.u, 32), vx = __shfl_xor(a1.u, 32);
        unsigned wx = __shfl_xor(a2.u, 32), zx = __shfl_xor(a3.u, 32);
        F8u pb;
        pb.u[0] = hi ? wx : a0.u;   // k = 8*hi + {0,1}
        pb.u[1] = hi ? zx : a1.u;   // k = 8*hi + {2,3}
        pb.u[2] = hi ? a2.u : ux;   // k = 8*hi + {4,5}
        pb.u[3] = hi ? a3.u : vx;   // k = 8*hi + {6,7}
        int vb = ((2 * s + hi) << 4);
        f16x8 vf0 = *(const f16x8*)((const char*)Vlds[cur] + lq * 128 + (vb ^ ((lq & 7) << 4)));
        f16x8 vf1 =
            *(const f16x8*)((const char*)Vlds[cur] + (32 + lq) * 128 + (vb ^ ((lq & 7) << 4)));
        o0 = mfma32(vf0, pb.v, o0);
        o1 = mfma32(vf1, pb.v, o1);
      }
    }
    __syncthreads();  // drains next-tile staging; uniform across waves
  }

  store_out();  // shallow-phase output
}

// ---------------- launch ----------------
extern "C" void kernel_launch(void* const* d_in, const int* in_sizes, int n_in,
                              void* d_out, int out_size, void* d_ws, size_t ws_size,
                              hipStream_t stream) {
  const float* x = (const float*)d_in[0];
  const float* Wqkv = (const float*)d_in[1];
  const float* bqkv = (const float*)d_in[2];
  const float* Wout = (const float*)d_in[3];
  const float* bout = (const float*)d_in[4];
  float* out = (float*)d_out;

  char* ws = (char*)d_ws;
  f16* xh = (f16*)(ws);                               // 16.78 MB  [8192][1024]
  f16* qkh = (f16*)(ws + 16777216);                   // 33.55 MB  [8192][2048] (Q|K)
  f16* vt = (f16*)(ws + 16777216 + 33554432);         // 16.78 MB  [4096][2048] (V^T)
  f16* wqkvT = (f16*)(ws + 16777216 + 33554432 + 16777216);            // 6.29 MB
  f16* woutT = (f16*)(ws + 16777216 + 33554432 + 16777216 + 6291456);  // 2.10 MB
  f16* attno = xh;  // reuse x_h region (dead after GEMM1)

  cvt_f16_kernel<<<(M_TOK * DM / 8 + 255) / 256, 256, 0, stream>>>(x, xh, M_TOK * DM / 8);
  transpose_cvt_kernel<<<dim3(3 * DM / 32, DM / 32), 256, 0, stream>>>(Wqkv, wqkvT, DM, 3 * DM);
  transpose_cvt_kernel<<<dim3(DM / 32, DM / 32), 256, 0, stream>>>(Wout, woutT, DM, DM);
  gemm_tn<f16, true><<<dim3(3 * DM / 128, M_TOK / 128), 256, 0, stream>>>(
      xh, wqkvT, bqkv, qkh, vt, M_TOK, 3 * DM, DM, 2048);
  attn_kernel<<<512, 256, 0, stream>>>(qkh, vt, attno);
  gemm_tn<float, false><<<dim3(DM / 128, M_TOK / 128), 256, 0, stream>>>(
      attno, woutT, bout, out, nullptr, M_TOK, DM, DM, DM);
}